// Round 1
// baseline (670.219 us; speedup 1.0000x reference)
//
#include <hip/hip_runtime.h>
#include <hip/hip_bf16.h>

#define L_SEQ 40
#define B_SZ  16
#define V_SZ  10000
#define V_PAD 10240
#define NPAIR 780
#define NROWP 784                 // 780 pairs + 1 init row + 3 pad "pairs"
#define M_ROWS (NROWP * B_SZ)     // 12544 rows, = 98 * 128

typedef __attribute__((ext_vector_type(8))) short short8;
typedef __attribute__((ext_vector_type(4))) float f32x4;

__device__ __forceinline__ unsigned short f2bf(float f) {
    unsigned int u = __float_as_uint(f);
    unsigned int r = u + 0x7FFFu + ((u >> 16) & 1u);
    return (unsigned short)(r >> 16);
}

// ---------------------------------------------------------------------------
// P1: transpose Ww2 [256, 10000] -> WwT fp32 [10240, 256] and WbT bf16 [10240,256]
// ---------------------------------------------------------------------------
__global__ void transpose_w2(const float* __restrict__ Ww2,
                             float* __restrict__ WwT,
                             unsigned short* __restrict__ WbT) {
    __shared__ float tile[32][33];
    int v0 = blockIdx.x * 32;   // vocab tile
    int k0 = blockIdx.y * 32;   // hidden tile
    int tx = threadIdx.x;       // 0..31
    int ty = threadIdx.y;       // 0..7
#pragma unroll
    for (int r = 0; r < 4; r++) {
        int k = k0 + ty + r * 8;
        int v = v0 + tx;
        float val = (v < V_SZ) ? Ww2[k * V_SZ + v] : 0.0f;
        tile[ty + r * 8][tx] = val;
    }
    __syncthreads();
#pragma unroll
    for (int r = 0; r < 4; r++) {
        int vrow = ty + r * 8;
        float val = tile[tx][vrow];
        int out_idx = (v0 + vrow) * 256 + (k0 + tx);
        WwT[out_idx] = val;
        WbT[out_idx] = f2bf(val);
    }
}

// ---------------------------------------------------------------------------
// P2: UV = h[640,512] @ {Wt1_top, Wt1_bot, Ww1_top, Ww1_bot} -> 4 x [640,256]
// ---------------------------------------------------------------------------
__global__ void uv_gemm(const float* __restrict__ h,
                        const float* __restrict__ Wt1,
                        const float* __restrict__ Ww1,
                        float* __restrict__ out4) {
    int n = threadIdx.x;            // 0..255
    int which = blockIdx.y;         // 0:Ut 1:Vt 2:Uw 3:Vw
    int m0 = blockIdx.x * 8;
    const float* W = (which < 2) ? Wt1 : Ww1;
    int foff = (which & 1) ? 512 : 0;
    float acc[8] = {0, 0, 0, 0, 0, 0, 0, 0};
    for (int f = 0; f < 512; f++) {
        float bv = W[(f + foff) * 256 + n];
#pragma unroll
        for (int r = 0; r < 8; r++) acc[r] += h[(m0 + r) * 512 + f] * bv;
    }
    float* dst = out4 + (size_t)which * 640 * 256;
#pragma unroll
    for (int r = 0; r < 8; r++) dst[(m0 + r) * 256 + n] = acc[r];
}

// ---------------------------------------------------------------------------
// A2: per (pair,b) row: X=tanh(Uw[i]+Vw[j]+bw1) (store bf16),
//     tlog = tanh(Ut[i]+Vt[j]+bt1).Wt2 + bt2 (fp32 exact),
//     glog = X . Ww2[:,tgt] + bw2[tgt]       (fp32 exact)
// one wave per row; row = p*16 + b; p==780 is the init cell (i=j=0)
// ---------------------------------------------------------------------------
__global__ void build_rows(const float* __restrict__ UV,
                           const int* __restrict__ sentence,
                           const float* __restrict__ bt1,
                           const float* __restrict__ bw1,
                           const float* __restrict__ Wt2,
                           const float* __restrict__ bt2,
                           const float* __restrict__ WwT,
                           const float* __restrict__ bw2,
                           unsigned short* __restrict__ X,
                           float* __restrict__ tlog,
                           float* __restrict__ glog) {
    int w = blockIdx.x * 4 + (threadIdx.x >> 6);   // global wave id = row
    int lane = threadIdx.x & 63;
    int p = w >> 4, b = w & 15;
    int i = 0, j = 0;
    if (p < NPAIR) {
        int rem = p, len = L_SEQ - 1;
        while (rem >= len) { rem -= len; len--; i++; }
        j = i + 1 + rem;
    }
    int j1 = (j + 1 < L_SEQ) ? j + 1 : L_SEQ - 1;
    int tgt = sentence[j1 * B_SZ + b];
    const float* Ut = UV + 0 * 640 * 256;
    const float* Vt = UV + 1 * 640 * 256;
    const float* Uw = UV + 2 * 640 * 256;
    const float* Vw = UV + 3 * 640 * 256;
    const float* ut = Ut + (i * B_SZ + b) * 256;
    const float* vt = Vt + (j * B_SZ + b) * 256;
    const float* uw = Uw + (i * B_SZ + b) * 256;
    const float* vw = Vw + (j * B_SZ + b) * 256;
    const float* wcol = WwT + (size_t)tgt * 256;
    float td = 0.f, gd = 0.f;
#pragma unroll
    for (int q = 0; q < 4; q++) {
        int k = q * 64 + lane;
        float xt = tanhf(ut[k] + vt[k] + bt1[k]);
        float xw = tanhf(uw[k] + vw[k] + bw1[k]);
        td += xt * Wt2[k];
        gd += xw * wcol[k];
        X[(size_t)w * 256 + k] = f2bf(xw);
    }
#pragma unroll
    for (int off = 32; off >= 1; off >>= 1) {
        td += __shfl_xor(td, off);
        gd += __shfl_xor(gd, off);
    }
    if (lane == 0) {
        tlog[w] = td + bt2[0];
        glog[w] = gd + bw2[tgt];
    }
}

// ---------------------------------------------------------------------------
// Big fused GEMM + sum-exp:  logits = X[12544,256] @ WbT^T (+bw2),
// rowsum[row] += sum_col exp(logit).  bf16 MFMA 16x16x32, no max-shift needed
// (|logit| <~ 20, safe in fp32). 128x128 tile, 4 waves of 64x64.
// A/B fragments loaded directly from global (cacheline-perfect pattern).
// ---------------------------------------------------------------------------
__global__ __launch_bounds__(256) void big_gemm(
        const unsigned short* __restrict__ X,
        const unsigned short* __restrict__ WbT,
        const float* __restrict__ bw2,
        float* __restrict__ rowsum) {
    int wid = threadIdx.x >> 6;
    int lane = threadIdx.x & 63;
    int l15 = lane & 15, l4 = lane >> 4;
    int RM = blockIdx.y * 128 + (wid >> 1) * 64;
    int CN = blockIdx.x * 128 + (wid & 1) * 64;

    f32x4 acc[4][4] = {};
    for (int kk = 0; kk < 256; kk += 32) {
        short8 a[4], bf[4];
#pragma unroll
        for (int mi = 0; mi < 4; mi++)
            a[mi] = *(const short8*)(X + (size_t)(RM + mi * 16 + l15) * 256 + kk + l4 * 8);
#pragma unroll
        for (int ni = 0; ni < 4; ni++)
            bf[ni] = *(const short8*)(WbT + (size_t)(CN + ni * 16 + l15) * 256 + kk + l4 * 8);
#pragma unroll
        for (int mi = 0; mi < 4; mi++)
#pragma unroll
            for (int ni = 0; ni < 4; ni++)
                acc[mi][ni] = __builtin_amdgcn_mfma_f32_16x16x32_bf16(
                    a[mi], bf[ni], acc[mi][ni], 0, 0, 0);
    }
    // epilogue: exp + per-row reduce over this tile's 64 columns per wave
#pragma unroll
    for (int mi = 0; mi < 4; mi++) {
#pragma unroll
        for (int r = 0; r < 4; r++) {
            float s = 0.f;
#pragma unroll
            for (int ni = 0; ni < 4; ni++) {
                int col = CN + ni * 16 + l15;
                if (col < V_SZ) {
                    float logit = acc[mi][ni][r] + bw2[col];
                    s += __expf(logit);
                }
            }
#pragma unroll
            for (int off = 1; off < 16; off <<= 1) s += __shfl_xor(s, off);
            if (l15 == 0) {
                int row = RM + mi * 16 + l4 * 4 + r;
                atomicAdd(&rowsum[row], s);
            }
        }
    }
}

// ---------------------------------------------------------------------------
// C: build SHW / RE / T-init tables [40,40,16]
// ---------------------------------------------------------------------------
__global__ void build_tables(const float* __restrict__ tlog,
                             const float* __restrict__ glog,
                             const float* __restrict__ rowsum,
                             float* __restrict__ SHW,
                             float* __restrict__ RE,
                             float* __restrict__ T) {
    int idx = blockIdx.x * 256 + threadIdx.x;
    if (idx >= L_SEQ * L_SEQ * B_SZ) return;
    int b = idx & 15;
    int j = (idx >> 4) % L_SEQ;
    int i = idx / (L_SEQ * B_SZ);
    const float NEGINF = -__builtin_inff();
    float shw = NEGINF, re = NEGINF;
    if (i < j) {
        int p = i * (2 * (L_SEQ - 1) - i + 1) / 2 + (j - i - 1);
        int row = p * 16 + b;
        float t = tlog[row];
        // log_sigmoid(t) and log_sigmoid(-t), numerically stable
        float re_v = (t >= 0.f) ? -log1pf(__expf(-t)) : (t - log1pf(__expf(t)));
        float sh_v = (t <= 0.f) ? -log1pf(__expf(t)) : (-t - log1pf(__expf(-t)));
        float wlp = glog[row] - __logf(rowsum[row]);
        shw = sh_v + wlp;
        re = re_v;
    }
    SHW[idx] = shw;
    RE[idx] = re;
    float tv = NEGINF;
    if (i == 0 && j == 1) {
        int row = NPAIR * 16 + b;  // init row
        tv = glog[row] - __logf(rowsum[row]);
    } else if (j == i + 1 && i >= 1) {
        tv = 0.f;
    }
    T[idx] = tv;
}

// ---------------------------------------------------------------------------
// D: CKY DP, single workgroup, online logsumexp per cell
// ---------------------------------------------------------------------------
__global__ void dp_kernel(const float* __restrict__ SHW,
                          const float* __restrict__ RE,
                          float* __restrict__ T,
                          float* __restrict__ out) {
    for (int gap = 2; gap <= L_SEQ - 1; gap++) {
        int n_i = L_SEQ - gap;
        int cells = n_i * B_SZ;
        for (int c = threadIdx.x; c < cells; c += blockDim.x) {
            int i = c >> 4;
            int b = c & 15;
            int j = i + gap;
            float m = -__builtin_inff(), ssum = 0.f;
            for (int k = i + 1; k < j; k++) {
                float s = T[(i * L_SEQ + k) * B_SZ + b] + T[(k * L_SEQ + j) * B_SZ + b]
                        + SHW[(i * L_SEQ + k) * B_SZ + b] + RE[(k * L_SEQ + j) * B_SZ + b];
                if (s > m) {
                    ssum = ssum * __expf(m - s) + 1.f;
                    m = s;
                } else {
                    ssum += __expf(s - m);
                }
            }
            T[(i * L_SEQ + j) * B_SZ + b] = m + __logf(ssum);
        }
        __syncthreads();
    }
    if (threadIdx.x < B_SZ)
        out[threadIdx.x] = T[(0 * L_SEQ + (L_SEQ - 1)) * B_SZ + threadIdx.x];
}

// ---------------------------------------------------------------------------
extern "C" void kernel_launch(void* const* d_in, const int* in_sizes, int n_in,
                              void* d_out, int out_size, void* d_ws, size_t ws_size,
                              hipStream_t stream) {
    const float* h        = (const float*)d_in[0];
    const int*   sentence = (const int*)d_in[1];
    const float* Wt1      = (const float*)d_in[2];
    const float* bt1      = (const float*)d_in[3];
    const float* Wt2      = (const float*)d_in[4];
    const float* bt2      = (const float*)d_in[5];
    const float* Ww1      = (const float*)d_in[6];
    const float* bw1      = (const float*)d_in[7];
    const float* Ww2      = (const float*)d_in[8];
    const float* bw2      = (const float*)d_in[9];
    float* out = (float*)d_out;

    char* ws = (char*)d_ws;
    size_t off = 0;
    float* UV = (float*)(ws + off);            off += 4ull * 640 * 256 * 4;      // 2.62 MB
    unsigned short* X = (unsigned short*)(ws + off);   off += (size_t)M_ROWS * 256 * 2;  // 6.42 MB
    unsigned short* WbT = (unsigned short*)(ws + off); off += (size_t)V_PAD * 256 * 2;   // 5.24 MB
    float* WwT = (float*)(ws + off);           off += (size_t)V_PAD * 256 * 4;   // 10.49 MB
    float* rowsum = (float*)(ws + off);        off += (size_t)M_ROWS * 4;
    float* tlog = (float*)(ws + off);          off += (size_t)M_ROWS * 4;
    float* glog = (float*)(ws + off);          off += (size_t)M_ROWS * 4;
    float* SHW = (float*)(ws + off);           off += 40 * 40 * 16 * 4;
    float* RE  = (float*)(ws + off);           off += 40 * 40 * 16 * 4;
    float* T   = (float*)(ws + off);           off += 40 * 40 * 16 * 4;

    hipMemsetAsync(rowsum, 0, (size_t)M_ROWS * 4, stream);

    transpose_w2<<<dim3(V_PAD / 32, 8), dim3(32, 8), 0, stream>>>(Ww2, WwT, WbT);
    uv_gemm<<<dim3(80, 4), 256, 0, stream>>>(h, Wt1, Ww1, UV);
    build_rows<<<M_ROWS / 4, 256, 0, stream>>>(UV, sentence, bt1, bw1, Wt2, bt2,
                                               WwT, bw2, X, tlog, glog);
    big_gemm<<<dim3(V_PAD / 128, M_ROWS / 128), 256, 0, stream>>>(X, WbT, bw2, rowsum);
    build_tables<<<(L_SEQ * L_SEQ * B_SZ + 255) / 256, 256, 0, stream>>>(
        tlog, glog, rowsum, SHW, RE, T);
    dp_kernel<<<1, 640, 0, stream>>>(SHW, RE, T, out);
}

// Round 2
// 347.479 us; speedup vs baseline: 1.9288x; 1.9288x over previous
//
#include <hip/hip_runtime.h>
#include <hip/hip_bf16.h>

#define L_SEQ 40
#define B_SZ  16
#define V_SZ  10000
#define V_PAD 10240
#define NPAIR 780
#define NROWP 784                 // 780 pairs + 1 init row + 3 pad "pairs"
#define M_ROWS (NROWP * B_SZ)     // 12544 rows, = 196 * 64

typedef __attribute__((ext_vector_type(8))) short short8;
typedef __attribute__((ext_vector_type(4))) float f32x4;

__device__ __forceinline__ unsigned short f2bf(float f) {
    unsigned int u = __float_as_uint(f);
    unsigned int r = u + 0x7FFFu + ((u >> 16) & 1u);
    return (unsigned short)(r >> 16);
}

// ---------------------------------------------------------------------------
// P1: transpose Ww2 [256, 10000] -> WwT fp32 [10240, 256] and WbT bf16 [10240,256]
// ---------------------------------------------------------------------------
__global__ void transpose_w2(const float* __restrict__ Ww2,
                             float* __restrict__ WwT,
                             unsigned short* __restrict__ WbT) {
    __shared__ float tile[32][33];
    int v0 = blockIdx.x * 32;   // vocab tile
    int k0 = blockIdx.y * 32;   // hidden tile
    int tx = threadIdx.x;       // 0..31
    int ty = threadIdx.y;       // 0..7
#pragma unroll
    for (int r = 0; r < 4; r++) {
        int k = k0 + ty + r * 8;
        int v = v0 + tx;
        float val = (v < V_SZ) ? Ww2[k * V_SZ + v] : 0.0f;
        tile[ty + r * 8][tx] = val;
    }
    __syncthreads();
#pragma unroll
    for (int r = 0; r < 4; r++) {
        int vrow = ty + r * 8;
        float val = tile[tx][vrow];
        int out_idx = (v0 + vrow) * 256 + (k0 + tx);
        WwT[out_idx] = val;
        WbT[out_idx] = f2bf(val);
    }
}

// ---------------------------------------------------------------------------
// P2: UV = h[640,512] @ {Wt1_top, Wt1_bot, Ww1_top, Ww1_bot} -> 4 x [640,256]
// LDS-staged h rows, f unrolled x4 for ILP.
// ---------------------------------------------------------------------------
__global__ __launch_bounds__(256) void uv_gemm(const float* __restrict__ h,
                        const float* __restrict__ Wt1,
                        const float* __restrict__ Ww1,
                        float* __restrict__ out4) {
    __shared__ float hs[8 * 512];   // 16 KB
    const int t = threadIdx.x;      // = output column n
    const int which = blockIdx.y;   // 0:Ut 1:Vt 2:Uw 3:Vw
    const int m0 = blockIdx.x * 8;
    const float4* src = (const float4*)(h + (size_t)m0 * 512);
    float4* dst4 = (float4*)hs;
#pragma unroll
    for (int v = 0; v < 4; v++) dst4[v * 256 + t] = src[v * 256 + t];
    __syncthreads();
    const float* W = ((which < 2) ? Wt1 : Ww1) + ((which & 1) ? 512 * 256 : 0);
    float acc[8] = {};
    for (int f = 0; f < 512; f += 4) {
        float w0 = W[(f + 0) * 256 + t];
        float w1 = W[(f + 1) * 256 + t];
        float w2 = W[(f + 2) * 256 + t];
        float w3 = W[(f + 3) * 256 + t];
#pragma unroll
        for (int r = 0; r < 8; r++) {
            acc[r] += hs[r * 512 + f] * w0 + hs[r * 512 + f + 1] * w1
                    + hs[r * 512 + f + 2] * w2 + hs[r * 512 + f + 3] * w3;
        }
    }
    float* dst = out4 + ((size_t)which * 640 + m0) * 256;
#pragma unroll
    for (int r = 0; r < 8; r++) dst[r * 256 + t] = acc[r];
}

// ---------------------------------------------------------------------------
// A2: per (pair,b) row: X=tanh(Uw[i]+Vw[j]+bw1) (store bf16),
//     tlog/glog in fp32 exact. One wave per row; p==780 is the init cell.
// ---------------------------------------------------------------------------
__global__ void build_rows(const float* __restrict__ UV,
                           const int* __restrict__ sentence,
                           const float* __restrict__ bt1,
                           const float* __restrict__ bw1,
                           const float* __restrict__ Wt2,
                           const float* __restrict__ bt2,
                           const float* __restrict__ WwT,
                           const float* __restrict__ bw2,
                           unsigned short* __restrict__ X,
                           float* __restrict__ tlog,
                           float* __restrict__ glog) {
    int w = blockIdx.x * 4 + (threadIdx.x >> 6);   // global wave id = row
    int lane = threadIdx.x & 63;
    int p = w >> 4, b = w & 15;
    int i = 0, j = 0;
    if (p < NPAIR) {
        int rem = p, len = L_SEQ - 1;
        while (rem >= len) { rem -= len; len--; i++; }
        j = i + 1 + rem;
    }
    int j1 = (j + 1 < L_SEQ) ? j + 1 : L_SEQ - 1;
    int tgt = sentence[j1 * B_SZ + b];
    const float* Ut = UV + 0 * 640 * 256;
    const float* Vt = UV + 1 * 640 * 256;
    const float* Uw = UV + 2 * 640 * 256;
    const float* Vw = UV + 3 * 640 * 256;
    const float* ut = Ut + (i * B_SZ + b) * 256;
    const float* vt = Vt + (j * B_SZ + b) * 256;
    const float* uw = Uw + (i * B_SZ + b) * 256;
    const float* vw = Vw + (j * B_SZ + b) * 256;
    const float* wcol = WwT + (size_t)tgt * 256;
    float td = 0.f, gd = 0.f;
#pragma unroll
    for (int q = 0; q < 4; q++) {
        int k = q * 64 + lane;
        float xt = tanhf(ut[k] + vt[k] + bt1[k]);
        float xw = tanhf(uw[k] + vw[k] + bw1[k]);
        td += xt * Wt2[k];
        gd += xw * wcol[k];
        X[(size_t)w * 256 + k] = f2bf(xw);
    }
#pragma unroll
    for (int off = 32; off >= 1; off >>= 1) {
        td += __shfl_xor(td, off);
        gd += __shfl_xor(gd, off);
    }
    if (lane == 0) {
        tlog[w] = td + bt2[0];
        glog[w] = gd + bw2[tgt];
    }
}

// ---------------------------------------------------------------------------
// Big fused GEMM + sum-exp, strip-mined.
// Grid (8 col-groups, 196 row-strips). Block = 256 thr = 4 waves.
// A strip (64x256 bf16, 32KB) staged ONCE into LDS via global_load_lds with
// XOR granule swizzle (breaks the 16-way conflict of the 512B row stride).
// Each wave: 64 cols; loops 5 column tiles x 8 k-steps = 40 barrier-free
// MFMA iterations; B frags direct-global with register double-buffer
// prefetch; per-lane rowsum partials accumulated in registers; ONE
// butterfly+atomic sequence per wave at the end.
// ---------------------------------------------------------------------------
__global__ __launch_bounds__(256) void big_gemm(
        const unsigned short* __restrict__ X,
        const unsigned short* __restrict__ WbT,
        const float* __restrict__ bw2,
        float* __restrict__ rowsum) {
    __shared__ short As[64 * 256];   // 32 KB
    const int t = threadIdx.x;
    const int wid = t >> 6;
    const int lane = t & 63;
    const int l15 = lane & 15, l4 = lane >> 4;
    const int g = blockIdx.x;          // column group: 1280 cols
    const int RM0 = blockIdx.y * 64;   // row strip

    // ---- stage A (64 rows x 256 cols bf16) with granule swizzle ----
    {
        const char* Xg = (const char*)(X + (size_t)RM0 * 256);
#pragma unroll
        for (int q = 0; q < 8; q++) {
            int flat = (wid * 8 + q) * 1024;       // chunk byte base (wave-uniform)
            int flatL = flat + lane * 16;          // this lane's dest byte
            int r = flatL >> 9;                    // dest row (512 B/row)
            int sg = (flatL >> 4) & 31;            // dest 16B-granule in row
            int cg = sg ^ (r & 7);                 // swizzled source granule
            __builtin_amdgcn_global_load_lds(
                (const __attribute__((address_space(1))) unsigned int*)(Xg + (r << 9) + (cg << 4)),
                (__attribute__((address_space(3))) unsigned int*)((char*)As + flat),
                16, 0, 0);
        }
    }
    __syncthreads();

    const int cwave0 = g * 1280 + wid * 64;
    const int xorv = l15 & 7;

    f32x4 acc[4][4] = {};
    float PS[4][4] = {};

    short8 bbuf[2][4];
#pragma unroll
    for (int ni = 0; ni < 4; ni++)
        bbuf[0][ni] = *(const short8*)(WbT + (size_t)(cwave0 + ni * 16 + l15) * 256 + l4 * 8);

    for (int ct = 0; ct < 5; ct++) {
        const int cb = cwave0 + ct * 256;
#pragma unroll
        for (int kk = 0; kk < 8; kk++) {
            // prefetch next iteration's B frags (last prefetch reads pad rows)
            const int ncb = (kk == 7) ? cb + 256 : cb;
            const int nk = (kk == 7) ? 0 : kk + 1;
#pragma unroll
            for (int ni = 0; ni < 4; ni++)
                bbuf[(kk + 1) & 1][ni] = *(const short8*)(WbT
                    + (size_t)(ncb + ni * 16 + l15) * 256 + nk * 32 + l4 * 8);
            // A frags from LDS (swizzled addresses)
            short8 a[4];
#pragma unroll
            for (int mi = 0; mi < 4; mi++) {
                int idx = (mi * 16 + l15) * 256 + (((kk * 4 + l4) ^ xorv) << 3);
                a[mi] = *(const short8*)(As + idx);
            }
#pragma unroll
            for (int mi = 0; mi < 4; mi++)
#pragma unroll
                for (int ni = 0; ni < 4; ni++)
                    acc[mi][ni] = __builtin_amdgcn_mfma_f32_16x16x32_bf16(
                        a[mi], bbuf[kk & 1][ni], acc[mi][ni], 0, 0, 0);
        }
        // epilogue for this column tile: bias + exp, accumulate into PS regs
#pragma unroll
        for (int ni = 0; ni < 4; ni++) {
            int col = cb + ni * 16 + l15;
            bool ok = (col < V_SZ);
            float bias = ok ? bw2[col] : 0.f;
#pragma unroll
            for (int mi = 0; mi < 4; mi++)
#pragma unroll
                for (int r = 0; r < 4; r++)
                    PS[mi][r] += ok ? __expf(acc[mi][ni][r] + bias) : 0.f;
        }
#pragma unroll
        for (int mi = 0; mi < 4; mi++)
#pragma unroll
            for (int ni = 0; ni < 4; ni++)
                acc[mi][ni] = f32x4{0.f, 0.f, 0.f, 0.f};
    }
    // single butterfly + atomics at wave end
#pragma unroll
    for (int mi = 0; mi < 4; mi++)
#pragma unroll
        for (int r = 0; r < 4; r++) {
            float v = PS[mi][r];
#pragma unroll
            for (int off = 1; off < 16; off <<= 1) v += __shfl_xor(v, off);
            if (l15 == 0) atomicAdd(&rowsum[RM0 + mi * 16 + l4 * 4 + r], v);
        }
}

// ---------------------------------------------------------------------------
// C: build SHW / RE / T-init tables [40,40,16]
// ---------------------------------------------------------------------------
__global__ void build_tables(const float* __restrict__ tlog,
                             const float* __restrict__ glog,
                             const float* __restrict__ rowsum,
                             float* __restrict__ SHW,
                             float* __restrict__ RE,
                             float* __restrict__ T) {
    int idx = blockIdx.x * 256 + threadIdx.x;
    if (idx >= L_SEQ * L_SEQ * B_SZ) return;
    int b = idx & 15;
    int j = (idx >> 4) % L_SEQ;
    int i = idx / (L_SEQ * B_SZ);
    const float NEGINF = -__builtin_inff();
    float shw = NEGINF, re = NEGINF;
    if (i < j) {
        int p = i * (2 * (L_SEQ - 1) - i + 1) / 2 + (j - i - 1);
        int row = p * 16 + b;
        float tl = tlog[row];
        float re_v = (tl >= 0.f) ? -log1pf(__expf(-tl)) : (tl - log1pf(__expf(tl)));
        float sh_v = (tl <= 0.f) ? -log1pf(__expf(tl)) : (-tl - log1pf(__expf(-tl)));
        float wlp = glog[row] - __logf(rowsum[row]);
        shw = sh_v + wlp;
        re = re_v;
    }
    SHW[idx] = shw;
    RE[idx] = re;
    float tv = NEGINF;
    if (i == 0 && j == 1) {
        int row = NPAIR * 16 + b;  // init row
        tv = glog[row] - __logf(rowsum[row]);
    } else if (j == i + 1 && i >= 1) {
        tv = 0.f;
    }
    T[idx] = tv;
}

// ---------------------------------------------------------------------------
// D: CKY DP. 16 blocks (one per batch), tables in LDS, 8 lanes per cell
// parallelize the split loop with shuffle-merged online logsumexp.
// ---------------------------------------------------------------------------
__global__ __launch_bounds__(512) void dp_kernel(const float* __restrict__ SHW,
                          const float* __restrict__ RE,
                          const float* __restrict__ T,
                          float* __restrict__ out) {
    __shared__ float Tl[1600], SHWl[1600], REl[1600];
    const int t = threadIdx.x;
    const int b = blockIdx.x;
    const float NEGINF = -__builtin_inff();
    for (int idx = t; idx < 1600; idx += 512) {
        Tl[idx] = T[idx * 16 + b];
        SHWl[idx] = SHW[idx * 16 + b];
        REl[idx] = RE[idx * 16 + b];
    }
    __syncthreads();
    const int tg = t >> 3, li = t & 7;
    for (int gap = 2; gap <= L_SEQ - 1; gap++) {
        int n_i = L_SEQ - gap;
        float m = NEGINF, s = 0.f;
        int i = tg, j = tg + gap;
        if (tg < n_i) {
            for (int k = i + 1 + li; k < j; k += 8) {
                float v = Tl[i * 40 + k] + Tl[k * 40 + j]
                        + SHWl[i * 40 + k] + REl[k * 40 + j];
                if (v > m) { s = s * __expf(m - v) + 1.f; m = v; }
                else s += __expf(v - m);
            }
        }
#pragma unroll
        for (int off = 1; off < 8; off <<= 1) {
            float mo = __shfl_xor(m, off), so = __shfl_xor(s, off);
            float M = fmaxf(m, mo);
            float sn = 0.f;
            if (m > NEGINF) sn += s * __expf(m - M);
            if (mo > NEGINF) sn += so * __expf(mo - M);
            m = M; s = sn;
        }
        if (tg < n_i && li == 0) Tl[i * 40 + j] = m + __logf(s);
        __syncthreads();
    }
    if (t == 0) out[b] = Tl[39];
}

// ---------------------------------------------------------------------------
extern "C" void kernel_launch(void* const* d_in, const int* in_sizes, int n_in,
                              void* d_out, int out_size, void* d_ws, size_t ws_size,
                              hipStream_t stream) {
    const float* h        = (const float*)d_in[0];
    const int*   sentence = (const int*)d_in[1];
    const float* Wt1      = (const float*)d_in[2];
    const float* bt1      = (const float*)d_in[3];
    const float* Wt2      = (const float*)d_in[4];
    const float* bt2      = (const float*)d_in[5];
    const float* Ww1      = (const float*)d_in[6];
    const float* bw1      = (const float*)d_in[7];
    const float* Ww2      = (const float*)d_in[8];
    const float* bw2      = (const float*)d_in[9];
    float* out = (float*)d_out;

    char* ws = (char*)d_ws;
    size_t off = 0;
    float* UV = (float*)(ws + off);            off += 4ull * 640 * 256 * 4;
    unsigned short* X = (unsigned short*)(ws + off);   off += (size_t)M_ROWS * 256 * 2;
    unsigned short* WbT = (unsigned short*)(ws + off); off += (size_t)(V_PAD + 512) * 256 * 2;  // +pad for last prefetch
    float* WwT = (float*)(ws + off);           off += (size_t)V_PAD * 256 * 4;
    float* rowsum = (float*)(ws + off);        off += (size_t)M_ROWS * 4;
    float* tlog = (float*)(ws + off);          off += (size_t)M_ROWS * 4;
    float* glog = (float*)(ws + off);          off += (size_t)M_ROWS * 4;
    float* SHW = (float*)(ws + off);           off += 40 * 40 * 16 * 4;
    float* RE  = (float*)(ws + off);           off += 40 * 40 * 16 * 4;
    float* T   = (float*)(ws + off);           off += 40 * 40 * 16 * 4;

    hipMemsetAsync(rowsum, 0, (size_t)M_ROWS * 4, stream);

    transpose_w2<<<dim3(V_PAD / 32, 8), dim3(32, 8), 0, stream>>>(Ww2, WwT, WbT);
    uv_gemm<<<dim3(80, 4), 256, 0, stream>>>(h, Wt1, Ww1, UV);
    build_rows<<<M_ROWS / 4, 256, 0, stream>>>(UV, sentence, bt1, bw1, Wt2, bt2,
                                               WwT, bw2, X, tlog, glog);
    big_gemm<<<dim3(8, M_ROWS / 64), 256, 0, stream>>>(X, WbT, bw2, rowsum);
    build_tables<<<(L_SEQ * L_SEQ * B_SZ + 255) / 256, 256, 0, stream>>>(
        tlog, glog, rowsum, SHW, RE, T);
    dp_kernel<<<16, 512, 0, stream>>>(SHW, RE, T, out);
}